// Round 2
// baseline (10525.433 us; speedup 1.0000x reference)
//
#include <hip/hip_runtime.h>
#include <hip/hip_cooperative_groups.h>
#include <stdint.h>

namespace cg = cooperative_groups;

// M-RNN bidirectional GRU imputation for MI355X (gfx950).
// B=512, T=128, V=59, H=512. bf16 MFMA + fp32 state (state in registers).

typedef unsigned short ushort_t;
typedef __bf16 bf16x8 __attribute__((ext_vector_type(8)));
typedef float f32x4 __attribute__((ext_vector_type(4)));

__device__ __forceinline__ ushort_t f2bf(float f) {
    union { float f; uint32_t u; } c; c.f = f;
    uint32_t u = c.u;
    uint32_t r = (u + 0x7FFFu + ((u >> 16) & 1u)) >> 16;
    return (ushort_t)r;
}

// ---------------------------------------------------------------------------
// prep: zero history slot 0, bf16 weights, xcat panels, pcat panel, post weights
// ---------------------------------------------------------------------------
__global__ void prep_kernel(const float* __restrict__ values, const float* __restrict__ masks,
                            const float* __restrict__ deltas_f, const float* __restrict__ deltas_b,
                            const float* __restrict__ Wih, const float* __restrict__ Whh,
                            const float* __restrict__ Wh,
                            const float* __restrict__ Wf, const float* __restrict__ bf_,
                            const float* __restrict__ Wc, const float* __restrict__ bc,
                            const float* __restrict__ Wi, const float* __restrict__ bi,
                            ushort_t* __restrict__ xcat_f, ushort_t* __restrict__ xcat_b,
                            ushort_t* __restrict__ WhhB, ushort_t* __restrict__ WihB,
                            ushort_t* __restrict__ WhpB,
                            ushort_t* __restrict__ hf0, ushort_t* __restrict__ hb0,
                            float* __restrict__ hstate,
                            ushort_t* __restrict__ pcat,
                            ushort_t* __restrict__ Wpost1, ushort_t* __restrict__ Wpost2,
                            float* __restrict__ bcP, float* __restrict__ biP)
{
    long long gid = (long long)blockIdx.x * blockDim.x + threadIdx.x;
    long long stride = (long long)gridDim.x * blockDim.x;

    for (long long i = gid; i < 1024LL * 512; i += stride) hstate[i] = 0.f;
    for (long long i = gid; i < 512LL * 512; i += stride) { hf0[i] = 0; hb0[i] = 0; }
    for (long long i = gid; i < 1536LL * 512; i += stride) WhhB[i] = f2bf(Whh[i]);
    for (long long i = gid; i < 1536LL * 192; i += stride) {
        int n = (int)(i / 192), c = (int)(i % 192);
        WihB[i] = (c < 177) ? f2bf(Wih[n * 177 + c]) : (ushort_t)0;
    }
    for (long long i = gid; i < 64LL * 1024; i += stride) {
        int n = (int)(i >> 10), k = (int)(i & 1023);
        WhpB[i] = (n < 59) ? f2bf(Wh[n * 1024 + k]) : (ushort_t)0;
    }
    // post weights: Wpost1[64][192] = [Wf*(1-I) | Wc[:, :59] | Wc[:, 59:]], pad 0
    for (long long i = gid; i < 64LL * 192; i += stride) {
        int n = (int)(i / 192), c = (int)(i % 192);
        float w = 0.f;
        if (n < 59) {
            if (c < 59)       w = (c == n) ? 0.f : Wf[n * 59 + c];
            else if (c < 118) w = Wc[n * 118 + (c - 59)];
            else if (c < 177) w = Wc[n * 118 + 59 + (c - 118)];
        }
        Wpost1[i] = f2bf(w);
    }
    for (long long i = gid; i < 64LL * 64; i += stride) {
        int n = (int)(i >> 6), k = (int)(i & 63);
        Wpost2[i] = (n < 59 && k < 59) ? f2bf(Wi[n * 59 + k]) : (ushort_t)0;
    }
    for (long long i = gid; i < 64; i += stride) {
        bcP[i] = (i < 59) ? (bf_[i] + bc[i]) : 0.f;
        biP[i] = (i < 59) ? bi[i] : 0.f;
    }
    // pcat[65536][192]: [values | (x_v later) | masks | 0]
    for (long long i = gid; i < 65536LL * 192; i += stride) {
        int c = (int)(i % 192);
        long long row = i / 192;            // = b*128 + t
        float v = 0.f;
        if (c < 59)            v = values[row * 59 + c];
        else if (c >= 118 && c < 177) v = masks[row * 59 + (c - 118)];
        if (c < 59 || (c >= 118 && c < 177)) pcat[i] = f2bf(v);
        else if (c >= 177) pcat[i] = 0;     // cols 59..117 written by xv
    }
    for (long long i = gid; i < 128LL * 512 * 192; i += stride) {
        int c = (int)(i % 192);
        long long tb = i / 192;
        int b = (int)(tb % 512);
        int t = (int)(tb / 512);
        float vf = 0.f;
        if (c < 59)       vf = values  [((long long)b * 128 + t) * 59 + c];
        else if (c < 118) vf = masks   [((long long)b * 128 + t) * 59 + (c - 59)];
        else if (c < 177) vf = deltas_f[((long long)b * 128 + t) * 59 + (c - 118)];
        xcat_f[i] = (c < 177) ? f2bf(vf) : (ushort_t)0;
        int tr = 127 - t;
        float vb = 0.f;
        if (c < 59)       vb = values  [((long long)b * 128 + tr) * 59 + c];
        else if (c < 118) vb = masks   [((long long)b * 128 + tr) * 59 + (c - 59)];
        else if (c < 177) vb = deltas_b[((long long)b * 128 + t)  * 59 + (c - 118)];
        xcat_b[i] = (c < 177) ? f2bf(vb) : (ushort_t)0;
    }
}

// ---------------------------------------------------------------------------
// Persistent cooperative recurrence: all 127 GRU steps, both directions.
// 256 blocks x 512 threads, 1 block/CU. Weights LDS-resident (96x704 bf16,
// padded rows 712). fp32 hidden state lives in registers (4/thread).
// A (h rows / xcat rows) double-buffered 64x64 chunks (padded rows 72).
// ---------------------------------------------------------------------------
#define BW_PITCH 712
#define AS_PITCH 72

__global__ __launch_bounds__(512)
void recurrence_kernel(const ushort_t* __restrict__ WhhB, const ushort_t* __restrict__ WihB,
                       const float* __restrict__ bih, const float* __restrict__ bhh,
                       const ushort_t* __restrict__ xcat_f, const ushort_t* __restrict__ xcat_b,
                       ushort_t* __restrict__ hfS, ushort_t* __restrict__ hbS)
{
    extern __shared__ char smem_c[];
    ushort_t* Bw = (ushort_t*)smem_c;                    // 96 x 712
    ushort_t* AsBuf = Bw + 96 * BW_PITCH;                // 2 x 64 x 72

    const int tid  = threadIdx.x;
    const int blk  = blockIdx.x;
    const int ublk = blk & 15;
    const int mblk = blk >> 4;
    const int u0   = ublk * 32;
    const bool fwd = (mblk < 8);
    const int rbase = (fwd ? mblk : mblk - 8) * 64;
    const ushort_t* xbase = fwd ? xcat_f : xcat_b;
    ushort_t* hS = fwd ? hfS : hbS;

    // preload weights: rows g*32+u -> [Whh(512) | Wih(192)]
    for (int i = tid; i < 96 * 88; i += 512) {
        int row = i / 88, q = i - row * 88;
        int g = row >> 5, u = u0 + (row & 31);
        const ushort_t* src = (q < 64)
            ? WhhB + ((size_t)(g * 512 + u)) * 512 + q * 8
            : WihB + ((size_t)(g * 512 + u)) * 192 + (q - 64) * 8;
        *(uint4*)&Bw[row * BW_PITCH + q * 8] = *(const uint4*)src;
    }

    const int lane = tid & 63, wv = tid >> 6;
    const int mt = wv >> 1, tc = wv & 1;
    const int l15 = lane & 15, lhi = lane >> 4;
    const int arow = tid >> 3, ac8 = (tid & 7) * 8;

    const int u = u0 + tc * 16 + l15;
    const float bR  = bih[u] + bhh[u];
    const float bZ  = bih[512 + u] + bhh[512 + u];
    const float bNX = bih[1024 + u];
    const float bNH = bhh[1024 + u];

    f32x4 hreg = {0.f, 0.f, 0.f, 0.f};
    f32x4 zero = {0.f, 0.f, 0.f, 0.f};

    cg::grid_group grid = cg::this_grid();
    __syncthreads();   // weights visible

    for (int t = 0; t < 127; ++t) {
        const ushort_t* hsrc = hS + (size_t)t * 512 * 512;
        const ushort_t* xsrc = xbase + (size_t)t * 512 * 192;
        ushort_t* hdst = hS + (size_t)(t + 1) * 512 * 512;

        f32x4 accR = zero, accZ = zero, accNH = zero, accNX = zero;

        // prologue: stage chunk 0
        uint4 areg = *(const uint4*)(hsrc + ((size_t)(rbase + arow)) * 512 + ac8);
        *(uint4*)&AsBuf[arow * AS_PITCH + ac8] = areg;
        __syncthreads();

        for (int c = 0; c < 11; ++c) {
            if (c < 10) {
                int cn = c + 1;
                const ushort_t* src = (cn < 8)
                    ? hsrc + ((size_t)(rbase + arow)) * 512 + cn * 64 + ac8
                    : xsrc + ((size_t)(rbase + arow)) * 192 + (cn - 8) * 64 + ac8;
                areg = *(const uint4*)src;
            }
            const ushort_t* Ab = AsBuf + (c & 1) * 64 * AS_PITCH;
            const int cbase = c * 64;
            #pragma unroll
            for (int ks = 0; ks < 64; ks += 32) {
                bf16x8 a  = *(const bf16x8*)&Ab[(mt * 16 + l15) * AS_PITCH + ks + lhi * 8];
                bf16x8 b0 = *(const bf16x8*)&Bw[( 0 + tc * 16 + l15) * BW_PITCH + cbase + ks + lhi * 8];
                bf16x8 b1 = *(const bf16x8*)&Bw[(32 + tc * 16 + l15) * BW_PITCH + cbase + ks + lhi * 8];
                bf16x8 b2 = *(const bf16x8*)&Bw[(64 + tc * 16 + l15) * BW_PITCH + cbase + ks + lhi * 8];
                accR = __builtin_amdgcn_mfma_f32_16x16x32_bf16(a, b0, accR, 0, 0, 0);
                accZ = __builtin_amdgcn_mfma_f32_16x16x32_bf16(a, b1, accZ, 0, 0, 0);
                if (c < 8) accNH = __builtin_amdgcn_mfma_f32_16x16x32_bf16(a, b2, accNH, 0, 0, 0);
                else       accNX = __builtin_amdgcn_mfma_f32_16x16x32_bf16(a, b2, accNX, 0, 0, 0);
            }
            __syncthreads();
            if (c < 10) {
                ushort_t* An = AsBuf + ((c + 1) & 1) * 64 * AS_PITCH;
                *(uint4*)&An[arow * AS_PITCH + ac8] = areg;
                __syncthreads();
            }
        }

        // GRU cell epilogue; state update in registers
        #pragma unroll
        for (int reg = 0; reg < 4; ++reg) {
            int m = rbase + mt * 16 + lhi * 4 + reg;   // row within direction
            float r = 1.f / (1.f + __expf(-(accR[reg] + bR)));
            float z = 1.f / (1.f + __expf(-(accZ[reg] + bZ)));
            float n = tanhf(accNX[reg] + bNX + r * (accNH[reg] + bNH));
            float hnew = (1.f - z) * n + z * hreg[reg];
            hreg[reg] = hnew;
            hdst[(size_t)m * 512 + u] = f2bf(hnew);
        }
        __threadfence();
        grid.sync();
    }
}

// ---------------------------------------------------------------------------
// Fallback step kernel (used only if cooperative launch unavailable)
// ---------------------------------------------------------------------------
__global__ __launch_bounds__(512)
void step_kernel(const ushort_t* __restrict__ hsrcF, const ushort_t* __restrict__ hsrcB,
                 ushort_t* __restrict__ hdstF, ushort_t* __restrict__ hdstB,
                 const ushort_t* __restrict__ xF, const ushort_t* __restrict__ xB,
                 const ushort_t* __restrict__ WhhB, const ushort_t* __restrict__ WihB,
                 const float* __restrict__ bih, const float* __restrict__ bhh,
                 float* __restrict__ hstate)
{
    __shared__ __align__(16) ushort_t As[64 * 64];
    __shared__ __align__(16) ushort_t Bs[96 * 64];

    const int tid  = threadIdx.x;
    const int ublk = blockIdx.x;
    const int mblk = blockIdx.y;
    const int u0   = ublk * 32;
    const bool fwd = (mblk < 8);
    const ushort_t* hsrc = fwd ? hsrcF : hsrcB;
    const ushort_t* xsrc = fwd ? xF : xB;
    ushort_t* hdst = fwd ? hdstF : hdstB;
    const int rbase = (fwd ? mblk : mblk - 8) * 64;

    const int lane = tid & 63, wv = tid >> 6;
    const int mt = wv >> 1, tc = wv & 1;
    const int l15 = lane & 15, lhi = lane >> 4;

    f32x4 zero = {0.f, 0.f, 0.f, 0.f};
    f32x4 accR = zero, accZ = zero, accNH = zero, accNX = zero;
    const int arow = tid >> 3, ac8 = (tid & 7) * 8;

    for (int chunk = 0; chunk < 11; ++chunk) {
        const bool ph1 = (chunk < 8);
        {
            const ushort_t* src = ph1
                ? hsrc + ((size_t)(rbase + arow)) * 512 + chunk * 64 + ac8
                : xsrc + ((size_t)(rbase + arow)) * 192 + (chunk - 8) * 64 + ac8;
            *(uint4*)&As[arow * 64 + ac8] = *(const uint4*)src;
        }
        {
            int rowB = tid >> 3; int c8 = (tid & 7) * 8;
            int g = rowB >> 5; int u = u0 + (rowB & 31);
            const ushort_t* src = ph1
                ? WhhB + ((size_t)(g * 512 + u)) * 512 + chunk * 64 + c8
                : WihB + ((size_t)(g * 512 + u)) * 192 + (chunk - 8) * 64 + c8;
            *(uint4*)&Bs[rowB * 64 + c8] = *(const uint4*)src;
            if (tid < 256) {
                int u2 = tid + 512;
                rowB = u2 >> 3; c8 = (u2 & 7) * 8;
                g = rowB >> 5; u = u0 + (rowB & 31);
                src = ph1
                    ? WhhB + ((size_t)(g * 512 + u)) * 512 + chunk * 64 + c8
                    : WihB + ((size_t)(g * 512 + u)) * 192 + (chunk - 8) * 64 + c8;
                *(uint4*)&Bs[rowB * 64 + c8] = *(const uint4*)src;
            }
        }
        __syncthreads();
        #pragma unroll
        for (int ks = 0; ks < 64; ks += 32) {
            bf16x8 a  = *(const bf16x8*)&As[(mt * 16 + l15) * 64 + ks + lhi * 8];
            bf16x8 b0 = *(const bf16x8*)&Bs[( 0 + tc * 16 + l15) * 64 + ks + lhi * 8];
            bf16x8 b1 = *(const bf16x8*)&Bs[(32 + tc * 16 + l15) * 64 + ks + lhi * 8];
            bf16x8 b2 = *(const bf16x8*)&Bs[(64 + tc * 16 + l15) * 64 + ks + lhi * 8];
            accR = __builtin_amdgcn_mfma_f32_16x16x32_bf16(a, b0, accR, 0, 0, 0);
            accZ = __builtin_amdgcn_mfma_f32_16x16x32_bf16(a, b1, accZ, 0, 0, 0);
            if (ph1) accNH = __builtin_amdgcn_mfma_f32_16x16x32_bf16(a, b2, accNH, 0, 0, 0);
            else     accNX = __builtin_amdgcn_mfma_f32_16x16x32_bf16(a, b2, accNX, 0, 0, 0);
        }
        __syncthreads();
    }

    const int u = u0 + tc * 16 + l15;
    const float bR  = bih[u] + bhh[u];
    const float bZ  = bih[512 + u] + bhh[512 + u];
    const float bNX = bih[1024 + u];
    const float bNH = bhh[1024 + u];
    #pragma unroll
    for (int reg = 0; reg < 4; ++reg) {
        int m = mblk * 64 + mt * 16 + lhi * 4 + reg;
        float r = 1.f / (1.f + __expf(-(accR[reg] + bR)));
        float z = 1.f / (1.f + __expf(-(accZ[reg] + bZ)));
        float n = tanhf(accNX[reg] + bNX + r * (accNH[reg] + bNH));
        size_t idx = (size_t)m * 512 + u;
        float hold = hstate[idx];
        float hnew = (1.f - z) * n + z * hold;
        hstate[idx] = hnew;
        size_t bloc = (size_t)(fwd ? m : m - 512) * 512 + u;
        hdst[bloc] = f2bf(hnew);
    }
}

// ---------------------------------------------------------------------------
// x_v = [hf, hb_rev] @ Wh^T + bh, written as bf16 into pcat cols 59..117
// ---------------------------------------------------------------------------
__global__ __launch_bounds__(256)
void xv_kernel(const ushort_t* __restrict__ hf, const ushort_t* __restrict__ hb,
               const ushort_t* __restrict__ WhpB, const float* __restrict__ bh,
               ushort_t* __restrict__ pcat)
{
    __shared__ __align__(16) ushort_t As[128 * 64];
    __shared__ __align__(16) ushort_t Bs[64 * 64];
    const int b = blockIdx.x;
    const int tid = threadIdx.x;
    const int lane = tid & 63, wv = tid >> 6;
    const int l15 = lane & 15, lhi = lane >> 4;

    f32x4 zero = {0.f, 0.f, 0.f, 0.f};
    f32x4 acc[2][4];
    #pragma unroll
    for (int i = 0; i < 2; ++i)
        #pragma unroll
        for (int j = 0; j < 4; ++j) acc[i][j] = zero;

    for (int chunk = 0; chunk < 16; ++chunk) {
        const bool fw = (chunk < 8);
        #pragma unroll
        for (int s = 0; s < 4; ++s) {
            int unit = tid + s * 256;
            int row = unit >> 3;
            int c8 = (unit & 7) * 8;
            const ushort_t* src = fw
                ? hf + ((size_t)row * 512 + b) * 512 + chunk * 64 + c8
                : hb + ((size_t)(127 - row) * 512 + b) * 512 + (chunk - 8) * 64 + c8;
            *(uint4*)&As[row * 64 + c8] = *(const uint4*)src;
        }
        #pragma unroll
        for (int s = 0; s < 2; ++s) {
            int unit = tid + s * 256;
            int row = unit >> 3;
            int c8 = (unit & 7) * 8;
            *(uint4*)&Bs[row * 64 + c8] =
                *(const uint4*)(WhpB + (size_t)row * 1024 + chunk * 64 + c8);
        }
        __syncthreads();
        #pragma unroll
        for (int ks = 0; ks < 64; ks += 32) {
            bf16x8 bfr[4];
            #pragma unroll
            for (int nt = 0; nt < 4; ++nt)
                bfr[nt] = *(const bf16x8*)&Bs[(nt * 16 + l15) * 64 + ks + lhi * 8];
            #pragma unroll
            for (int mt2 = 0; mt2 < 2; ++mt2) {
                bf16x8 a = *(const bf16x8*)&As[(wv * 32 + mt2 * 16 + l15) * 64 + ks + lhi * 8];
                #pragma unroll
                for (int nt = 0; nt < 4; ++nt)
                    acc[mt2][nt] = __builtin_amdgcn_mfma_f32_16x16x32_bf16(a, bfr[nt], acc[mt2][nt], 0, 0, 0);
            }
        }
        __syncthreads();
    }
    #pragma unroll
    for (int mt2 = 0; mt2 < 2; ++mt2) {
        #pragma unroll
        for (int nt = 0; nt < 4; ++nt) {
            int col = nt * 16 + l15;
            if (col < 59) {
                float bhc = bh[col];
                #pragma unroll
                for (int reg = 0; reg < 4; ++reg) {
                    int t = wv * 32 + mt2 * 16 + lhi * 4 + reg;
                    pcat[((size_t)b * 128 + t) * 192 + 59 + col] = f2bf(acc[mt2][nt][reg] + bhc);
                }
            }
        }
    }
}

// ---------------------------------------------------------------------------
// Fused post: two chained MFMA GEMMs (K=192 then K=64) + x_imp + loss partials.
// Block = 64 rows. Grid 1024 x 256 threads.
// ---------------------------------------------------------------------------
__global__ __launch_bounds__(256)
void post_kernel(const ushort_t* __restrict__ pcat,
                 const ushort_t* __restrict__ Wpost1, const ushort_t* __restrict__ Wpost2,
                 const float* __restrict__ bcP, const float* __restrict__ biP,
                 const float* __restrict__ values, const float* __restrict__ masks,
                 float* __restrict__ out, float* __restrict__ pnum, float* __restrict__ pden)
{
    __shared__ __align__(16) ushort_t A1[64 * 200];   // pcat tile, later reused as XH [64][72]
    __shared__ __align__(16) ushort_t B1[64 * 200];
    __shared__ __align__(16) ushort_t B2[64 * 72];

    const int tid = threadIdx.x;
    const int blk = blockIdx.x;
    const int lane = tid & 63, wv = tid >> 6;
    const int l15 = lane & 15, lhi = lane >> 4;

    // stage A1 (64x192), B1 (64x192), B2 (64x64)
    #pragma unroll
    for (int s = 0; s < 6; ++s) {
        int unit = tid + s * 256;                  // 0..1535
        int row = unit / 24, c8 = (unit % 24) * 8; // 192/8 = 24
        *(uint4*)&A1[row * 200 + c8] =
            *(const uint4*)(pcat + ((size_t)blk * 64 + row) * 192 + c8);
        *(uint4*)&B1[row * 200 + c8] =
            *(const uint4*)(Wpost1 + (size_t)row * 192 + c8);
    }
    #pragma unroll
    for (int s = 0; s < 2; ++s) {
        int unit = tid + s * 256;                  // 0..511
        int row = unit >> 3, c8 = (unit & 7) * 8;
        *(uint4*)&B2[row * 72 + c8] = *(const uint4*)(Wpost2 + (size_t)row * 64 + c8);
    }
    __syncthreads();

    f32x4 zero = {0.f, 0.f, 0.f, 0.f};
    f32x4 acc1[4];
    #pragma unroll
    for (int nt = 0; nt < 4; ++nt) acc1[nt] = zero;

    #pragma unroll
    for (int ks = 0; ks < 192; ks += 32) {
        bf16x8 a = *(const bf16x8*)&A1[(wv * 16 + l15) * 200 + ks + lhi * 8];
        #pragma unroll
        for (int nt = 0; nt < 4; ++nt) {
            bf16x8 bb = *(const bf16x8*)&B1[(nt * 16 + l15) * 200 + ks + lhi * 8];
            acc1[nt] = __builtin_amdgcn_mfma_f32_16x16x32_bf16(a, bb, acc1[nt], 0, 0, 0);
        }
    }
    __syncthreads();   // all A1 reads done; reuse as XH

    // xh = acc1 + bcomb -> bf16 into A1 region as [64][72]
    #pragma unroll
    for (int nt = 0; nt < 4; ++nt) {
        int col = nt * 16 + l15;
        float bcv = bcP[col];
        #pragma unroll
        for (int reg = 0; reg < 4; ++reg) {
            int row = wv * 16 + lhi * 4 + reg;
            A1[row * 72 + col] = f2bf(acc1[nt][reg] + bcv);
        }
    }
    __syncthreads();

    f32x4 acc2[4];
    #pragma unroll
    for (int nt = 0; nt < 4; ++nt) acc2[nt] = zero;
    #pragma unroll
    for (int ks = 0; ks < 64; ks += 32) {
        bf16x8 a = *(const bf16x8*)&A1[(wv * 16 + l15) * 72 + ks + lhi * 8];
        #pragma unroll
        for (int nt = 0; nt < 4; ++nt) {
            bf16x8 bb = *(const bf16x8*)&B2[(nt * 16 + l15) * 72 + ks + lhi * 8];
            acc2[nt] = __builtin_amdgcn_mfma_f32_16x16x32_bf16(a, bb, acc2[nt], 0, 0, 0);
        }
    }

    float biR[4];
    #pragma unroll
    for (int nt = 0; nt < 4; ++nt) biR[nt] = biP[nt * 16 + l15];

    #pragma unroll
    for (int reg = 0; reg < 4; ++reg) {
        size_t rowg = (size_t)blk * 64 + wv * 16 + lhi * 4 + reg;
        float esum = 0.f, dsum = 0.f;
        #pragma unroll
        for (int nt = 0; nt < 4; ++nt) {
            int col = nt * 16 + l15;
            if (col < 59) {
                float imp = acc2[nt][reg] + biR[nt];
                float v = values[rowg * 59 + col];
                float m = masks [rowg * 59 + col];
                out[rowg * 59 + col] = m * v + (1.f - m) * imp;
                esum += fabsf(v - imp) * m;
                dsum += m;
            }
        }
        #pragma unroll
        for (int o = 1; o < 16; o <<= 1) {
            esum += __shfl_xor(esum, o);
            dsum += __shfl_xor(dsum, o);
        }
        if (l15 == 0) { pnum[rowg] = esum; pden[rowg] = dsum; }
    }
}

// ---------------------------------------------------------------------------
// loss reduction: sum_t ( sum_b num / (sum_b den + 1e-5) )
// ---------------------------------------------------------------------------
__global__ void loss_kernel(const float* __restrict__ pnum, const float* __restrict__ pden,
                            float* __restrict__ out)
{
    __shared__ float red[128];
    int t = threadIdx.x;   // 0..127
    float sn = 0.f, sd = 0.f;
    for (int b = 0; b < 512; ++b) {
        sn += pnum[(size_t)b * 128 + t];
        sd += pden[(size_t)b * 128 + t];
    }
    red[t] = sn / (sd + 1e-5f);
    __syncthreads();
    if (t == 0) {
        float s = 0.f;
        for (int i = 0; i < 128; ++i) s += red[i];
        out[3866624] = s;   // B*T*V
    }
}

// ---------------------------------------------------------------------------
extern "C" void kernel_launch(void* const* d_in, const int* in_sizes, int n_in,
                              void* d_out, int out_size, void* d_ws, size_t ws_size,
                              hipStream_t stream)
{
    const float* values   = (const float*)d_in[0];
    const float* masks    = (const float*)d_in[1];
    const float* deltas_f = (const float*)d_in[2];
    const float* deltas_b = (const float*)d_in[3];
    const float* Wih = (const float*)d_in[4];
    const float* Whh = (const float*)d_in[5];
    const float* bih = (const float*)d_in[6];
    const float* bhh = (const float*)d_in[7];
    const float* Wh  = (const float*)d_in[8];
    const float* bh  = (const float*)d_in[9];
    const float* Wf  = (const float*)d_in[10];
    const float* bf_ = (const float*)d_in[11];
    const float* Wc  = (const float*)d_in[12];
    const float* bc  = (const float*)d_in[13];
    const float* Wi  = (const float*)d_in[14];
    const float* bi  = (const float*)d_in[15];
    float* out = (float*)d_out;

    uint8_t* ws = (uint8_t*)d_ws;
    size_t off = 0;
    auto alloc = [&](size_t bytes) -> void* {
        void* p = ws + off;
        off = (off + bytes + 255) & ~((size_t)255);
        return p;
    };
    ushort_t* xcat_f = (ushort_t*)alloc(128ULL * 512 * 192 * 2);
    ushort_t* xcat_b = (ushort_t*)alloc(128ULL * 512 * 192 * 2);
    ushort_t* WhhB   = (ushort_t*)alloc(1536ULL * 512 * 2);
    ushort_t* WihB   = (ushort_t*)alloc(1536ULL * 192 * 2);
    ushort_t* WhpB   = (ushort_t*)alloc(64ULL * 1024 * 2);
    ushort_t* hfS    = (ushort_t*)alloc(128ULL * 512 * 512 * 2);
    ushort_t* hbS    = (ushort_t*)alloc(128ULL * 512 * 512 * 2);
    float*    hstate = (float*)alloc(1024ULL * 512 * 4);
    ushort_t* pcat   = (ushort_t*)alloc(65536ULL * 192 * 2);
    ushort_t* Wpost1 = (ushort_t*)alloc(64ULL * 192 * 2);
    ushort_t* Wpost2 = (ushort_t*)alloc(64ULL * 64 * 2);
    float*    bcP    = (float*)alloc(64 * 4);
    float*    biP    = (float*)alloc(64 * 4);
    float*    pnum   = (float*)alloc(65536ULL * 4);
    float*    pden   = (float*)alloc(65536ULL * 4);

    prep_kernel<<<2048, 256, 0, stream>>>(values, masks, deltas_f, deltas_b, Wih, Whh, Wh,
                                          Wf, bf_, Wc, bc, Wi, bi,
                                          xcat_f, xcat_b, WhhB, WihB, WhpB,
                                          hfS, hbS, hstate,
                                          pcat, Wpost1, Wpost2, bcP, biP);

    // Recurrence: persistent cooperative kernel (fallback: 127 step launches)
    const unsigned smemBytes = (96u * BW_PITCH + 2u * 64u * AS_PITCH) * 2u;  // 155136 B
    hipError_t aerr = hipFuncSetAttribute((const void*)recurrence_kernel,
                                          hipFuncAttributeMaxDynamicSharedMemorySize,
                                          (int)smemBytes);
    hipError_t lerr = hipErrorUnknown;
    if (aerr == hipSuccess) {
        const ushort_t* a0 = WhhB; const ushort_t* a1 = WihB;
        const float* a2 = bih; const float* a3 = bhh;
        const ushort_t* a4 = xcat_f; const ushort_t* a5 = xcat_b;
        ushort_t* a6 = hfS; ushort_t* a7 = hbS;
        void* args[] = { &a0, &a1, &a2, &a3, &a4, &a5, &a6, &a7 };
        lerr = hipLaunchCooperativeKernel((const void*)recurrence_kernel,
                                          dim3(256), dim3(512), args, smemBytes, stream);
    }
    if (lerr != hipSuccess) {
        for (int t = 0; t < 127; ++t) {
            step_kernel<<<dim3(16, 16), 512, 0, stream>>>(
                hfS + (size_t)t * 512 * 512, hbS + (size_t)t * 512 * 512,
                hfS + (size_t)(t + 1) * 512 * 512, hbS + (size_t)(t + 1) * 512 * 512,
                xcat_f + (size_t)t * 512 * 192, xcat_b + (size_t)t * 512 * 192,
                WhhB, WihB, bih, bhh, hstate);
        }
    }

    xv_kernel<<<512, 256, 0, stream>>>(hfS, hbS, WhpB, bh, pcat);
    post_kernel<<<1024, 256, 0, stream>>>(pcat, Wpost1, Wpost2, bcP, biP,
                                          values, masks, out, pnum, pden);
    loss_kernel<<<1, 128, 0, stream>>>(pnum, pden, out);
}

// Round 3
// 1517.900 us; speedup vs baseline: 6.9342x; 6.9342x over previous
//
#include <hip/hip_runtime.h>
#include <stdint.h>

// M-RNN bidirectional GRU imputation for MI355X (gfx950).
// B=512, T=128, V=59, H=512. bf16 MFMA + fp32 state in registers.
// Persistent cooperative recurrence kernel with custom MALL-coherent barrier.

typedef unsigned short ushort_t;
typedef __bf16 bf16x8 __attribute__((ext_vector_type(8)));
typedef float f32x4 __attribute__((ext_vector_type(4)));
typedef unsigned int u32x4 __attribute__((ext_vector_type(4)));

__device__ __forceinline__ ushort_t f2bf(float f) {
    union { float f; uint32_t u; } c; c.f = f;
    uint32_t u = c.u;
    uint32_t r = (u + 0x7FFFu + ((u >> 16) & 1u)) >> 16;
    return (ushort_t)r;
}

// MALL-coherent (bypass L1+L2) load/store — h-state lines never enter caches,
// so cross-XCD visibility needs no wbl2/inv. Loads complete at a later
// explicit s_waitcnt vmcnt(N); keep single-assign single-use register flow.
__device__ __forceinline__ u32x4 load_b128_mall(const void* p) {
    u32x4 d;
    asm volatile("global_load_dwordx4 %0, %1, off sc0 sc1"
                 : "=v"(d) : "v"(p) : "memory");
    return d;
}
__device__ __forceinline__ void store_b16_mall(void* p, unsigned v) {
    asm volatile("global_store_short %0, %1, off sc0 sc1"
                 :: "v"(p), "v"(v) : "memory");
}

// ---------------------------------------------------------------------------
// prep: zero slot-0 / barrier, bf16 weights, xcat panels, pcat panel, post wts
// ---------------------------------------------------------------------------
__global__ void prep_kernel(const float* __restrict__ values, const float* __restrict__ masks,
                            const float* __restrict__ deltas_f, const float* __restrict__ deltas_b,
                            const float* __restrict__ Wih, const float* __restrict__ Whh,
                            const float* __restrict__ Wh,
                            const float* __restrict__ Wf, const float* __restrict__ bf_,
                            const float* __restrict__ Wc, const float* __restrict__ bc,
                            const float* __restrict__ Wi, const float* __restrict__ bi,
                            ushort_t* __restrict__ xcat_f, ushort_t* __restrict__ xcat_b,
                            ushort_t* __restrict__ WhhB, ushort_t* __restrict__ WihB,
                            ushort_t* __restrict__ WhpB,
                            ushort_t* __restrict__ hf0, ushort_t* __restrict__ hb0,
                            float* __restrict__ hstate,
                            ushort_t* __restrict__ pcat,
                            ushort_t* __restrict__ Wpost1, ushort_t* __restrict__ Wpost2,
                            float* __restrict__ bcP, float* __restrict__ biP,
                            unsigned* __restrict__ bar)
{
    long long gid = (long long)blockIdx.x * blockDim.x + threadIdx.x;
    long long stride = (long long)gridDim.x * blockDim.x;

    if (gid == 0) bar[0] = 0u;
    for (long long i = gid; i < 1024LL * 512; i += stride) hstate[i] = 0.f;
    for (long long i = gid; i < 512LL * 512; i += stride) { hf0[i] = 0; hb0[i] = 0; }
    for (long long i = gid; i < 1536LL * 512; i += stride) WhhB[i] = f2bf(Whh[i]);
    for (long long i = gid; i < 1536LL * 192; i += stride) {
        int n = (int)(i / 192), c = (int)(i % 192);
        WihB[i] = (c < 177) ? f2bf(Wih[n * 177 + c]) : (ushort_t)0;
    }
    for (long long i = gid; i < 64LL * 1024; i += stride) {
        int n = (int)(i >> 10), k = (int)(i & 1023);
        WhpB[i] = (n < 59) ? f2bf(Wh[n * 1024 + k]) : (ushort_t)0;
    }
    for (long long i = gid; i < 64LL * 192; i += stride) {
        int n = (int)(i / 192), c = (int)(i % 192);
        float w = 0.f;
        if (n < 59) {
            if (c < 59)       w = (c == n) ? 0.f : Wf[n * 59 + c];
            else if (c < 118) w = Wc[n * 118 + (c - 59)];
            else if (c < 177) w = Wc[n * 118 + 59 + (c - 118)];
        }
        Wpost1[i] = f2bf(w);
    }
    for (long long i = gid; i < 64LL * 64; i += stride) {
        int n = (int)(i >> 6), k = (int)(i & 63);
        Wpost2[i] = (n < 59 && k < 59) ? f2bf(Wi[n * 59 + k]) : (ushort_t)0;
    }
    for (long long i = gid; i < 64; i += stride) {
        bcP[i] = (i < 59) ? (bf_[i] + bc[i]) : 0.f;
        biP[i] = (i < 59) ? bi[i] : 0.f;
    }
    for (long long i = gid; i < 65536LL * 192; i += stride) {
        int c = (int)(i % 192);
        long long row = i / 192;
        float v = 0.f;
        if (c < 59)            v = values[row * 59 + c];
        else if (c >= 118 && c < 177) v = masks[row * 59 + (c - 118)];
        if (c < 59 || (c >= 118 && c < 177)) pcat[i] = f2bf(v);
        else if (c >= 177) pcat[i] = 0;
    }
    for (long long i = gid; i < 128LL * 512 * 192; i += stride) {
        int c = (int)(i % 192);
        long long tb = i / 192;
        int b = (int)(tb % 512);
        int t = (int)(tb / 512);
        float vf = 0.f;
        if (c < 59)       vf = values  [((long long)b * 128 + t) * 59 + c];
        else if (c < 118) vf = masks   [((long long)b * 128 + t) * 59 + (c - 59)];
        else if (c < 177) vf = deltas_f[((long long)b * 128 + t) * 59 + (c - 118)];
        xcat_f[i] = (c < 177) ? f2bf(vf) : (ushort_t)0;
        int tr = 127 - t;
        float vb = 0.f;
        if (c < 59)       vb = values  [((long long)b * 128 + tr) * 59 + c];
        else if (c < 118) vb = masks   [((long long)b * 128 + tr) * 59 + (c - 59)];
        else if (c < 177) vb = deltas_b[((long long)b * 128 + t)  * 59 + (c - 118)];
        xcat_b[i] = (c < 177) ? f2bf(vb) : (ushort_t)0;
    }
}

// ---------------------------------------------------------------------------
// Persistent recurrence: 127 GRU steps, both directions.
// 256 blocks x 512 thr, 1 block/CU. Weights LDS-resident, XOR-swizzled.
// Custom barrier: atomicAdd + agent-scope spin; h I/O MALL-coherent (sc0 sc1).
// LDS: Bw 96x704 (135168 B) + As 2x64x64 (16384 B) = 151552 B.
// ---------------------------------------------------------------------------
__global__ __launch_bounds__(512)
void recurrence_kernel(const ushort_t* __restrict__ WhhB, const ushort_t* __restrict__ WihB,
                       const float* __restrict__ bih, const float* __restrict__ bhh,
                       const ushort_t* __restrict__ xcat_f, const ushort_t* __restrict__ xcat_b,
                       ushort_t* __restrict__ hfS, ushort_t* __restrict__ hbS,
                       unsigned* __restrict__ bar)
{
    extern __shared__ char smem_c[];
    ushort_t* Bw = (ushort_t*)smem_c;          // 96 rows x 704, col-chunk swizzled
    ushort_t* As = Bw + 96 * 704;              // 2 x 64 x 64, swizzled

    const int tid  = threadIdx.x;
    const int blk  = blockIdx.x;
    const int ublk = blk & 15;
    const int mblk = blk >> 4;
    const int u0   = ublk * 32;
    const bool fwd = (mblk < 8);
    const int rbase = (fwd ? mblk : mblk - 8) * 64;
    const ushort_t* xbase = fwd ? xcat_f : xcat_b;
    ushort_t* hS = fwd ? hfS : hbS;

    // weight preload (normal cached loads)
    for (int i = tid; i < 96 * 88; i += 512) {
        int row = i / 88, q = i - row * 88;
        int g = row >> 5, u = u0 + (row & 31);
        const ushort_t* src = (q < 64)
            ? WhhB + ((size_t)(g * 512 + u)) * 512 + q * 8
            : WihB + ((size_t)(g * 512 + u)) * 192 + (q - 64) * 8;
        int qs = q ^ (row & 7);
        *(u32x4*)&Bw[row * 704 + qs * 8] = *(const u32x4*)src;
    }

    const int lane = tid & 63, wv = tid >> 6;
    const int mt = wv >> 1, tc = wv & 1;
    const int l15 = lane & 15, lhi = lane >> 4;
    const int arow = tid >> 3, aj = tid & 7;
    const int awoff = arow * 64 + ((aj ^ (arow & 7)) * 8);
    const int aSw = l15 & 7;

    const int u = u0 + tc * 16 + l15;
    const float bR  = bih[u] + bhh[u];
    const float bZ  = bih[512 + u] + bhh[512 + u];
    const float bNX = bih[1024 + u];
    const float bNH = bhh[1024 + u];

    f32x4 hreg = {0.f, 0.f, 0.f, 0.f};
    f32x4 zero = {0.f, 0.f, 0.f, 0.f};

    __syncthreads();   // weights staged + biases loaded

    for (int t = 0; t < 127; ++t) {
        const ushort_t* hsrc = hS + (size_t)t * 262144;
        const ushort_t* xsrc = xbase + (size_t)t * 98304;
        ushort_t* hdst = hS + (size_t)(t + 1) * 262144;

        const ushort_t* hrow = hsrc + (size_t)(rbase + arow) * 512 + aj * 8;
        const ushort_t* xrow = xsrc + (size_t)(rbase + arow) * 192 + aj * 8;

        f32x4 accR = zero, accZ = zero, accNH = zero, accNX = zero;
        u32x4 r[3];

        // depth-3 prefetch prologue
        r[0] = load_b128_mall(hrow);
        r[1] = load_b128_mall(hrow + 64);
        r[2] = load_b128_mall(hrow + 128);
        asm volatile("s_waitcnt vmcnt(2)" ::: "memory");
        *(u32x4*)&As[awoff] = r[0];
        __syncthreads();

        #pragma unroll
        for (int c = 0; c < 11; ++c) {
            // MFMA on chunk c from As[c&1]
            const ushort_t* Ab = As + (c & 1) * 4096;
            #pragma unroll
            for (int ks = 0; ks < 64; ks += 32) {
                int j  = (ks >> 3) + lhi;
                int jB = c * 8 + j;
                bf16x8 a  = *(const bf16x8*)&Ab[(mt * 16 + l15) * 64 + ((j ^ aSw) * 8)];
                bf16x8 b0 = *(const bf16x8*)&Bw[( 0 + tc * 16 + l15) * 704 + ((jB ^ aSw) * 8)];
                bf16x8 b1 = *(const bf16x8*)&Bw[(32 + tc * 16 + l15) * 704 + ((jB ^ aSw) * 8)];
                bf16x8 b2 = *(const bf16x8*)&Bw[(64 + tc * 16 + l15) * 704 + ((jB ^ aSw) * 8)];
                accR = __builtin_amdgcn_mfma_f32_16x16x32_bf16(a, b0, accR, 0, 0, 0);
                accZ = __builtin_amdgcn_mfma_f32_16x16x32_bf16(a, b1, accZ, 0, 0, 0);
                if (c < 8) accNH = __builtin_amdgcn_mfma_f32_16x16x32_bf16(a, b2, accNH, 0, 0, 0);
                else       accNX = __builtin_amdgcn_mfma_f32_16x16x32_bf16(a, b2, accNX, 0, 0, 0);
            }
            // issue prefetch for chunk c+3
            if (c + 3 <= 10) {
                int k = c + 3;
                const ushort_t* src = (k < 8) ? (hrow + k * 64) : (xrow + (k - 8) * 64);
                r[(c + 3) % 3] = load_b128_mall(src);
            }
            // stage chunk c+1 into the other LDS buffer
            if (c < 10) {
                if (c <= 7)      { asm volatile("s_waitcnt vmcnt(2)" ::: "memory"); }
                else if (c == 8) { asm volatile("s_waitcnt vmcnt(1)" ::: "memory"); }
                else             { asm volatile("s_waitcnt vmcnt(0)" ::: "memory"); }
                *(u32x4*)&As[((c + 1) & 1) * 4096 + awoff] = r[(c + 1) % 3];
                __syncthreads();
            }
        }

        // GRU cell epilogue; fp32 state in registers; h out via MALL stores
        #pragma unroll
        for (int reg = 0; reg < 4; ++reg) {
            int m = rbase + mt * 16 + lhi * 4 + reg;
            float rr = 1.f / (1.f + __expf(-(accR[reg] + bR)));
            float zz = 1.f / (1.f + __expf(-(accZ[reg] + bZ)));
            float nn = tanhf(accNX[reg] + bNX + rr * (accNH[reg] + bNH));
            float hnew = (1.f - zz) * nn + zz * hreg[reg];
            hreg[reg] = hnew;
            store_b16_mall(hdst + (size_t)m * 512 + u, (unsigned)f2bf(hnew));
        }

        if (t < 126) {
            asm volatile("s_waitcnt vmcnt(0)" ::: "memory");  // h stores at MALL
            __syncthreads();
            if (tid == 0) {
                atomicAdd(bar, 1u);
                unsigned target = (unsigned)(t + 1) * 256u;
                while (__hip_atomic_load(bar, __ATOMIC_RELAXED,
                                         __HIP_MEMORY_SCOPE_AGENT) < target)
                    __builtin_amdgcn_s_sleep(4);
            }
            __syncthreads();
        }
    }
}

// ---------------------------------------------------------------------------
// Fallback step kernel (used only if cooperative launch unavailable)
// ---------------------------------------------------------------------------
__global__ __launch_bounds__(512)
void step_kernel(const ushort_t* __restrict__ hsrcF, const ushort_t* __restrict__ hsrcB,
                 ushort_t* __restrict__ hdstF, ushort_t* __restrict__ hdstB,
                 const ushort_t* __restrict__ xF, const ushort_t* __restrict__ xB,
                 const ushort_t* __restrict__ WhhB, const ushort_t* __restrict__ WihB,
                 const float* __restrict__ bih, const float* __restrict__ bhh,
                 float* __restrict__ hstate)
{
    __shared__ __align__(16) ushort_t As[64 * 64];
    __shared__ __align__(16) ushort_t Bs[96 * 64];

    const int tid  = threadIdx.x;
    const int ublk = blockIdx.x;
    const int mblk = blockIdx.y;
    const int u0   = ublk * 32;
    const bool fwd = (mblk < 8);
    const ushort_t* hsrc = fwd ? hsrcF : hsrcB;
    const ushort_t* xsrc = fwd ? xF : xB;
    ushort_t* hdst = fwd ? hdstF : hdstB;
    const int rbase = (fwd ? mblk : mblk - 8) * 64;

    const int lane = tid & 63, wv = tid >> 6;
    const int mt = wv >> 1, tc = wv & 1;
    const int l15 = lane & 15, lhi = lane >> 4;

    f32x4 zero = {0.f, 0.f, 0.f, 0.f};
    f32x4 accR = zero, accZ = zero, accNH = zero, accNX = zero;
    const int arow = tid >> 3, ac8 = (tid & 7) * 8;

    for (int chunk = 0; chunk < 11; ++chunk) {
        const bool ph1 = (chunk < 8);
        {
            const ushort_t* src = ph1
                ? hsrc + ((size_t)(rbase + arow)) * 512 + chunk * 64 + ac8
                : xsrc + ((size_t)(rbase + arow)) * 192 + (chunk - 8) * 64 + ac8;
            *(uint4*)&As[arow * 64 + ac8] = *(const uint4*)src;
        }
        {
            int rowB = tid >> 3; int c8 = (tid & 7) * 8;
            int g = rowB >> 5; int u = u0 + (rowB & 31);
            const ushort_t* src = ph1
                ? WhhB + ((size_t)(g * 512 + u)) * 512 + chunk * 64 + c8
                : WihB + ((size_t)(g * 512 + u)) * 192 + (chunk - 8) * 64 + c8;
            *(uint4*)&Bs[rowB * 64 + c8] = *(const uint4*)src;
            if (tid < 256) {
                int u2 = tid + 512;
                rowB = u2 >> 3; c8 = (u2 & 7) * 8;
                g = rowB >> 5; u = u0 + (rowB & 31);
                src = ph1
                    ? WhhB + ((size_t)(g * 512 + u)) * 512 + chunk * 64 + c8
                    : WihB + ((size_t)(g * 512 + u)) * 192 + (chunk - 8) * 64 + c8;
                *(uint4*)&Bs[rowB * 64 + c8] = *(const uint4*)src;
            }
        }
        __syncthreads();
        #pragma unroll
        for (int ks = 0; ks < 64; ks += 32) {
            bf16x8 a  = *(const bf16x8*)&As[(mt * 16 + l15) * 64 + ks + lhi * 8];
            bf16x8 b0 = *(const bf16x8*)&Bs[( 0 + tc * 16 + l15) * 64 + ks + lhi * 8];
            bf16x8 b1 = *(const bf16x8*)&Bs[(32 + tc * 16 + l15) * 64 + ks + lhi * 8];
            bf16x8 b2 = *(const bf16x8*)&Bs[(64 + tc * 16 + l15) * 64 + ks + lhi * 8];
            accR = __builtin_amdgcn_mfma_f32_16x16x32_bf16(a, b0, accR, 0, 0, 0);
            accZ = __builtin_amdgcn_mfma_f32_16x16x32_bf16(a, b1, accZ, 0, 0, 0);
            if (ph1) accNH = __builtin_amdgcn_mfma_f32_16x16x32_bf16(a, b2, accNH, 0, 0, 0);
            else     accNX = __builtin_amdgcn_mfma_f32_16x16x32_bf16(a, b2, accNX, 0, 0, 0);
        }
        __syncthreads();
    }

    const int u = u0 + tc * 16 + l15;
    const float bR  = bih[u] + bhh[u];
    const float bZ  = bih[512 + u] + bhh[512 + u];
    const float bNX = bih[1024 + u];
    const float bNH = bhh[1024 + u];
    #pragma unroll
    for (int reg = 0; reg < 4; ++reg) {
        int m = mblk * 64 + mt * 16 + lhi * 4 + reg;
        float r = 1.f / (1.f + __expf(-(accR[reg] + bR)));
        float z = 1.f / (1.f + __expf(-(accZ[reg] + bZ)));
        float n = tanhf(accNX[reg] + bNX + r * (accNH[reg] + bNH));
        size_t idx = (size_t)m * 512 + u;
        float hold = hstate[idx];
        float hnew = (1.f - z) * n + z * hold;
        hstate[idx] = hnew;
        size_t bloc = (size_t)(fwd ? m : m - 512) * 512 + u;
        hdst[bloc] = f2bf(hnew);
    }
}

// ---------------------------------------------------------------------------
// x_v = [hf, hb_rev] @ Wh^T + bh, written as bf16 into pcat cols 59..117
// ---------------------------------------------------------------------------
__global__ __launch_bounds__(256)
void xv_kernel(const ushort_t* __restrict__ hf, const ushort_t* __restrict__ hb,
               const ushort_t* __restrict__ WhpB, const float* __restrict__ bh,
               ushort_t* __restrict__ pcat)
{
    __shared__ __align__(16) ushort_t As[128 * 64];
    __shared__ __align__(16) ushort_t Bs[64 * 64];
    const int b = blockIdx.x;
    const int tid = threadIdx.x;
    const int lane = tid & 63, wv = tid >> 6;
    const int l15 = lane & 15, lhi = lane >> 4;

    f32x4 zero = {0.f, 0.f, 0.f, 0.f};
    f32x4 acc[2][4];
    #pragma unroll
    for (int i = 0; i < 2; ++i)
        #pragma unroll
        for (int j = 0; j < 4; ++j) acc[i][j] = zero;

    for (int chunk = 0; chunk < 16; ++chunk) {
        const bool fw = (chunk < 8);
        #pragma unroll
        for (int s = 0; s < 4; ++s) {
            int unit = tid + s * 256;
            int row = unit >> 3;
            int c8 = (unit & 7) * 8;
            const ushort_t* src = fw
                ? hf + ((size_t)row * 512 + b) * 512 + chunk * 64 + c8
                : hb + ((size_t)(127 - row) * 512 + b) * 512 + (chunk - 8) * 64 + c8;
            *(uint4*)&As[row * 64 + c8] = *(const uint4*)src;
        }
        #pragma unroll
        for (int s = 0; s < 2; ++s) {
            int unit = tid + s * 256;
            int row = unit >> 3;
            int c8 = (unit & 7) * 8;
            *(uint4*)&Bs[row * 64 + c8] =
                *(const uint4*)(WhpB + (size_t)row * 1024 + chunk * 64 + c8);
        }
        __syncthreads();
        #pragma unroll
        for (int ks = 0; ks < 64; ks += 32) {
            bf16x8 bfr[4];
            #pragma unroll
            for (int nt = 0; nt < 4; ++nt)
                bfr[nt] = *(const bf16x8*)&Bs[(nt * 16 + l15) * 64 + ks + lhi * 8];
            #pragma unroll
            for (int mt2 = 0; mt2 < 2; ++mt2) {
                bf16x8 a = *(const bf16x8*)&As[(wv * 32 + mt2 * 16 + l15) * 64 + ks + lhi * 8];
                #pragma unroll
                for (int nt = 0; nt < 4; ++nt)
                    acc[mt2][nt] = __builtin_amdgcn_mfma_f32_16x16x32_bf16(a, bfr[nt], acc[mt2][nt], 0, 0, 0);
            }
        }
        __syncthreads();
    }
    #pragma unroll
    for (int mt2 = 0; mt2 < 2; ++mt2) {
        #pragma unroll
        for (int nt = 0; nt < 4; ++nt) {
            int col = nt * 16 + l15;
            if (col < 59) {
                float bhc = bh[col];
                #pragma unroll
                for (int reg = 0; reg < 4; ++reg) {
                    int t = wv * 32 + mt2 * 16 + lhi * 4 + reg;
                    pcat[((size_t)b * 128 + t) * 192 + 59 + col] = f2bf(acc[mt2][nt][reg] + bhc);
                }
            }
        }
    }
}

// ---------------------------------------------------------------------------
// Fused post: two chained MFMA GEMMs + x_imp + loss partials
// ---------------------------------------------------------------------------
__global__ __launch_bounds__(256)
void post_kernel(const ushort_t* __restrict__ pcat,
                 const ushort_t* __restrict__ Wpost1, const ushort_t* __restrict__ Wpost2,
                 const float* __restrict__ bcP, const float* __restrict__ biP,
                 const float* __restrict__ values, const float* __restrict__ masks,
                 float* __restrict__ out, float* __restrict__ pnum, float* __restrict__ pden)
{
    __shared__ __align__(16) ushort_t A1[64 * 200];
    __shared__ __align__(16) ushort_t B1[64 * 200];
    __shared__ __align__(16) ushort_t B2[64 * 72];

    const int tid = threadIdx.x;
    const int blk = blockIdx.x;
    const int lane = tid & 63, wv = tid >> 6;
    const int l15 = lane & 15, lhi = lane >> 4;

    #pragma unroll
    for (int s = 0; s < 6; ++s) {
        int unit = tid + s * 256;
        int row = unit / 24, c8 = (unit % 24) * 8;
        *(uint4*)&A1[row * 200 + c8] =
            *(const uint4*)(pcat + ((size_t)blk * 64 + row) * 192 + c8);
        *(uint4*)&B1[row * 200 + c8] =
            *(const uint4*)(Wpost1 + (size_t)row * 192 + c8);
    }
    #pragma unroll
    for (int s = 0; s < 2; ++s) {
        int unit = tid + s * 256;
        int row = unit >> 3, c8 = (unit & 7) * 8;
        *(uint4*)&B2[row * 72 + c8] = *(const uint4*)(Wpost2 + (size_t)row * 64 + c8);
    }
    __syncthreads();

    f32x4 zero = {0.f, 0.f, 0.f, 0.f};
    f32x4 acc1[4];
    #pragma unroll
    for (int nt = 0; nt < 4; ++nt) acc1[nt] = zero;

    #pragma unroll
    for (int ks = 0; ks < 192; ks += 32) {
        bf16x8 a = *(const bf16x8*)&A1[(wv * 16 + l15) * 200 + ks + lhi * 8];
        #pragma unroll
        for (int nt = 0; nt < 4; ++nt) {
            bf16x8 bb = *(const bf16x8*)&B1[(nt * 16 + l15) * 200 + ks + lhi * 8];
            acc1[nt] = __builtin_amdgcn_mfma_f32_16x16x32_bf16(a, bb, acc1[nt], 0, 0, 0);
        }
    }
    __syncthreads();

    #pragma unroll
    for (int nt = 0; nt < 4; ++nt) {
        int col = nt * 16 + l15;
        float bcv = bcP[col];
        #pragma unroll
        for (int reg = 0; reg < 4; ++reg) {
            int row = wv * 16 + lhi * 4 + reg;
            A1[row * 72 + col] = f2bf(acc1[nt][reg] + bcv);
        }
    }
    __syncthreads();

    f32x4 acc2[4];
    #pragma unroll
    for (int nt = 0; nt < 4; ++nt) acc2[nt] = zero;
    #pragma unroll
    for (int ks = 0; ks < 64; ks += 32) {
        bf16x8 a = *(const bf16x8*)&A1[(wv * 16 + l15) * 72 + ks + lhi * 8];
        #pragma unroll
        for (int nt = 0; nt < 4; ++nt) {
            bf16x8 bb = *(const bf16x8*)&B2[(nt * 16 + l15) * 72 + ks + lhi * 8];
            acc2[nt] = __builtin_amdgcn_mfma_f32_16x16x32_bf16(a, bb, acc2[nt], 0, 0, 0);
        }
    }

    float biR[4];
    #pragma unroll
    for (int nt = 0; nt < 4; ++nt) biR[nt] = biP[nt * 16 + l15];

    #pragma unroll
    for (int reg = 0; reg < 4; ++reg) {
        size_t rowg = (size_t)blk * 64 + wv * 16 + lhi * 4 + reg;
        float esum = 0.f, dsum = 0.f;
        #pragma unroll
        for (int nt = 0; nt < 4; ++nt) {
            int col = nt * 16 + l15;
            if (col < 59) {
                float imp = acc2[nt][reg] + biR[nt];
                float v = values[rowg * 59 + col];
                float m = masks [rowg * 59 + col];
                out[rowg * 59 + col] = m * v + (1.f - m) * imp;
                esum += fabsf(v - imp) * m;
                dsum += m;
            }
        }
        #pragma unroll
        for (int o = 1; o < 16; o <<= 1) {
            esum += __shfl_xor(esum, o);
            dsum += __shfl_xor(dsum, o);
        }
        if (l15 == 0) { pnum[rowg] = esum; pden[rowg] = dsum; }
    }
}

// ---------------------------------------------------------------------------
// loss reduction: sum_t ( sum_b num / (sum_b den + 1e-5) ), parallelized
// ---------------------------------------------------------------------------
__global__ __launch_bounds__(512)
void loss_kernel(const float* __restrict__ pnum, const float* __restrict__ pden,
                 float* __restrict__ out)
{
    __shared__ float sn[512], sd[512];
    int tid = threadIdx.x;
    int t = tid & 127, q = tid >> 7;   // q in 0..3
    float a = 0.f, b = 0.f;
    for (int i = 0; i < 128; ++i) {
        int bb = q * 128 + i;
        a += pnum[(size_t)bb * 128 + t];
        b += pden[(size_t)bb * 128 + t];
    }
    sn[tid] = a; sd[tid] = b;
    __syncthreads();
    if (q == 0) {
        float A = sn[t] + sn[128 + t] + sn[256 + t] + sn[384 + t];
        float B = sd[t] + sd[128 + t] + sd[256 + t] + sd[384 + t];
        sn[t] = A / (B + 1e-5f);
    }
    __syncthreads();
    if (tid == 0) {
        float s = 0.f;
        for (int i = 0; i < 128; ++i) s += sn[i];
        out[3866624] = s;   // B*T*V
    }
}

// ---------------------------------------------------------------------------
extern "C" void kernel_launch(void* const* d_in, const int* in_sizes, int n_in,
                              void* d_out, int out_size, void* d_ws, size_t ws_size,
                              hipStream_t stream)
{
    const float* values   = (const float*)d_in[0];
    const float* masks    = (const float*)d_in[1];
    const float* deltas_f = (const float*)d_in[2];
    const float* deltas_b = (const float*)d_in[3];
    const float* Wih = (const float*)d_in[4];
    const float* Whh = (const float*)d_in[5];
    const float* bih = (const float*)d_in[6];
    const float* bhh = (const float*)d_in[7];
    const float* Wh  = (const float*)d_in[8];
    const float* bh  = (const float*)d_in[9];
    const float* Wf  = (const float*)d_in[10];
    const float* bf_ = (const float*)d_in[11];
    const float* Wc  = (const float*)d_in[12];
    const float* bc  = (const float*)d_in[13];
    const float* Wi  = (const float*)d_in[14];
    const float* bi  = (const float*)d_in[15];
    float* out = (float*)d_out;

    uint8_t* ws = (uint8_t*)d_ws;
    size_t off = 0;
    auto alloc = [&](size_t bytes) -> void* {
        void* p = ws + off;
        off = (off + bytes + 255) & ~((size_t)255);
        return p;
    };
    ushort_t* xcat_f = (ushort_t*)alloc(128ULL * 512 * 192 * 2);
    ushort_t* xcat_b = (ushort_t*)alloc(128ULL * 512 * 192 * 2);
    ushort_t* WhhB   = (ushort_t*)alloc(1536ULL * 512 * 2);
    ushort_t* WihB   = (ushort_t*)alloc(1536ULL * 192 * 2);
    ushort_t* WhpB   = (ushort_t*)alloc(64ULL * 1024 * 2);
    ushort_t* hfS    = (ushort_t*)alloc(128ULL * 512 * 512 * 2);
    ushort_t* hbS    = (ushort_t*)alloc(128ULL * 512 * 512 * 2);
    float*    hstate = (float*)alloc(1024ULL * 512 * 4);
    ushort_t* pcat   = (ushort_t*)alloc(65536ULL * 192 * 2);
    ushort_t* Wpost1 = (ushort_t*)alloc(64ULL * 192 * 2);
    ushort_t* Wpost2 = (ushort_t*)alloc(64ULL * 64 * 2);
    float*    bcP    = (float*)alloc(64 * 4);
    float*    biP    = (float*)alloc(64 * 4);
    float*    pnum   = (float*)alloc(65536ULL * 4);
    float*    pden   = (float*)alloc(65536ULL * 4);
    unsigned* bar    = (unsigned*)alloc(256);

    prep_kernel<<<2048, 256, 0, stream>>>(values, masks, deltas_f, deltas_b, Wih, Whh, Wh,
                                          Wf, bf_, Wc, bc, Wi, bi,
                                          xcat_f, xcat_b, WhhB, WihB, WhpB,
                                          hfS, hbS, hstate,
                                          pcat, Wpost1, Wpost2, bcP, biP, bar);

    // Persistent recurrence (custom barrier); fallback: 127 step launches
    const unsigned smemBytes = (96u * 704u + 2u * 64u * 64u) * 2u;  // 151552 B
    hipError_t aerr = hipFuncSetAttribute((const void*)recurrence_kernel,
                                          hipFuncAttributeMaxDynamicSharedMemorySize,
                                          (int)smemBytes);
    hipError_t lerr = hipErrorUnknown;
    if (aerr == hipSuccess) {
        const ushort_t* a0 = WhhB; const ushort_t* a1 = WihB;
        const float* a2 = bih; const float* a3 = bhh;
        const ushort_t* a4 = xcat_f; const ushort_t* a5 = xcat_b;
        ushort_t* a6 = hfS; ushort_t* a7 = hbS;
        unsigned* a8 = bar;
        void* args[] = { &a0, &a1, &a2, &a3, &a4, &a5, &a6, &a7, &a8 };
        lerr = hipLaunchCooperativeKernel((const void*)recurrence_kernel,
                                          dim3(256), dim3(512), args, smemBytes, stream);
    }
    if (lerr != hipSuccess) {
        for (int t = 0; t < 127; ++t) {
            step_kernel<<<dim3(16, 16), 512, 0, stream>>>(
                hfS + (size_t)t * 512 * 512, hbS + (size_t)t * 512 * 512,
                hfS + (size_t)(t + 1) * 512 * 512, hbS + (size_t)(t + 1) * 512 * 512,
                xcat_f + (size_t)t * 512 * 192, xcat_b + (size_t)t * 512 * 192,
                WhhB, WihB, bih, bhh, hstate);
        }
    }

    xv_kernel<<<512, 256, 0, stream>>>(hfS, hbS, WhpB, bh, pcat);
    post_kernel<<<1024, 256, 0, stream>>>(pcat, Wpost1, Wpost2, bcP, biP,
                                          values, masks, out, pnum, pden);
    loss_kernel<<<1, 512, 0, stream>>>(pnum, pden, out);
}

// Round 4
// 856.818 us; speedup vs baseline: 12.2843x; 1.7716x over previous
//
#include <hip/hip_runtime.h>
#include <stdint.h>

// M-RNN bidirectional GRU imputation for MI355X (gfx950).
// B=512, T=128, V=59, H=512. bf16 MFMA + fp32 state in registers.
// Persistent recurrence kernel; per-mblk-group barriers (16 blocks each);
// h-state via MALL-coherent (sc0 sc1) ops so coherence never needs L2 flushes.

typedef unsigned short ushort_t;
typedef __bf16 bf16x8 __attribute__((ext_vector_type(8)));
typedef float f32x4 __attribute__((ext_vector_type(4)));
typedef unsigned int u32x4 __attribute__((ext_vector_type(4)));

__device__ __forceinline__ ushort_t f2bf(float f) {
    union { float f; uint32_t u; } c; c.f = f;
    uint32_t u = c.u;
    uint32_t r = (u + 0x7FFFu + ((u >> 16) & 1u)) >> 16;
    return (ushort_t)r;
}

// MALL-coherent (bypass L1+L2) load/store for cross-XCD-visible h-state.
__device__ __forceinline__ u32x4 load_b128_mall(const void* p) {
    u32x4 d;
    asm volatile("global_load_dwordx4 %0, %1, off sc0 sc1"
                 : "=v"(d) : "v"(p) : "memory");
    return d;
}
__device__ __forceinline__ void store_b16_mall(void* p, unsigned v) {
    asm volatile("global_store_short %0, %1, off sc0 sc1"
                 :: "v"(p), "v"(v) : "memory");
}

__device__ __forceinline__ float fast_sigmoid(float x) {
    float e = __expf(-x);
    return __builtin_amdgcn_rcpf(1.f + e);
}
__device__ __forceinline__ float fast_tanh(float x) {
    float xc = fminf(fmaxf(x, -15.f), 15.f);
    float e = __expf(-2.f * xc);
    return (1.f - e) * __builtin_amdgcn_rcpf(1.f + e);
}

// ---------------------------------------------------------------------------
// prep_small: barrier counters, slot-0 zeros, bf16 weights, post weights
// ---------------------------------------------------------------------------
__global__ void prep_small(const float* __restrict__ Wih, const float* __restrict__ Whh,
                           const float* __restrict__ Wh,
                           const float* __restrict__ Wf, const float* __restrict__ bf_,
                           const float* __restrict__ Wc, const float* __restrict__ bc,
                           const float* __restrict__ Wi, const float* __restrict__ bi,
                           ushort_t* __restrict__ WhhB, ushort_t* __restrict__ WihB,
                           ushort_t* __restrict__ WhpB,
                           ushort_t* __restrict__ hf0, ushort_t* __restrict__ hb0,
                           float* __restrict__ hstate,
                           ushort_t* __restrict__ Wpost1, ushort_t* __restrict__ Wpost2,
                           float* __restrict__ bcP, float* __restrict__ biP,
                           unsigned* __restrict__ bar)
{
    long long gid = (long long)blockIdx.x * blockDim.x + threadIdx.x;
    long long stride = (long long)gridDim.x * blockDim.x;

    for (long long i = gid; i < 16 * 64; i += stride) bar[i] = 0u;
    for (long long i = gid; i < 1024LL * 512; i += stride) hstate[i] = 0.f;
    for (long long i = gid; i < 512LL * 512; i += stride) { hf0[i] = 0; hb0[i] = 0; }
    for (long long i = gid; i < 1536LL * 512; i += stride) WhhB[i] = f2bf(Whh[i]);
    for (long long i = gid; i < 1536LL * 192; i += stride) {
        int n = (int)(i / 192), c = (int)(i % 192);
        WihB[i] = (c < 177) ? f2bf(Wih[n * 177 + c]) : (ushort_t)0;
    }
    for (long long i = gid; i < 64LL * 1024; i += stride) {
        int n = (int)(i >> 10), k = (int)(i & 1023);
        WhpB[i] = (n < 59) ? f2bf(Wh[n * 1024 + k]) : (ushort_t)0;
    }
    for (long long i = gid; i < 64LL * 192; i += stride) {
        int n = (int)(i / 192), c = (int)(i % 192);
        float w = 0.f;
        if (n < 59) {
            if (c < 59)       w = (c == n) ? 0.f : Wf[n * 59 + c];
            else if (c < 118) w = Wc[n * 118 + (c - 59)];
            else if (c < 177) w = Wc[n * 118 + 59 + (c - 118)];
        }
        Wpost1[i] = f2bf(w);
    }
    for (long long i = gid; i < 64LL * 64; i += stride) {
        int n = (int)(i >> 6), k = (int)(i & 63);
        Wpost2[i] = (n < 59 && k < 59) ? f2bf(Wi[n * 59 + k]) : (ushort_t)0;
    }
    for (long long i = gid; i < 64; i += stride) {
        bcP[i] = (i < 59) ? (bf_[i] + bc[i]) : 0.f;
        biP[i] = (i < 59) ? bi[i] : 0.f;
    }
}

// ---------------------------------------------------------------------------
// prep_panels: xcat_f / xcat_b / pcat, div-free (block = one (b,t) row)
// ---------------------------------------------------------------------------
__global__ __launch_bounds__(192)
void prep_panels(const float* __restrict__ values, const float* __restrict__ masks,
                 const float* __restrict__ deltas_f, const float* __restrict__ deltas_b,
                 ushort_t* __restrict__ xcat_f, ushort_t* __restrict__ xcat_b,
                 ushort_t* __restrict__ pcat)
{
    const int row = blockIdx.x;            // b*128 + t
    const int c = threadIdx.x;             // 0..191
    const int b = row >> 7, t = row & 127;
    const int tr = 127 - t;
    const long long rowr = (long long)b * 128 + tr;

    // xcat_f[t][b][c]
    float vf = 0.f;
    if (c < 59)       vf = values  [(long long)row * 59 + c];
    else if (c < 118) vf = masks   [(long long)row * 59 + (c - 59)];
    else if (c < 177) vf = deltas_f[(long long)row * 59 + (c - 118)];
    xcat_f[((size_t)t * 512 + b) * 192 + c] = (c < 177) ? f2bf(vf) : (ushort_t)0;

    // xcat_b[t][b][c]: values/masks time-flipped, deltas_b unflipped
    float vb = 0.f;
    if (c < 59)       vb = values  [rowr * 59 + c];
    else if (c < 118) vb = masks   [rowr * 59 + (c - 59)];
    else if (c < 177) vb = deltas_b[(long long)row * 59 + (c - 118)];
    xcat_b[((size_t)t * 512 + b) * 192 + c] = (c < 177) ? f2bf(vb) : (ushort_t)0;

    // pcat[row][c] = [values | (x_v by xv kernel) | masks | 0]
    if (c < 59)
        pcat[(size_t)row * 192 + c] = f2bf(values[(long long)row * 59 + c]);
    else if (c >= 118 && c < 177)
        pcat[(size_t)row * 192 + c] = f2bf(masks[(long long)row * 59 + (c - 118)]);
    else if (c >= 177)
        pcat[(size_t)row * 192 + c] = 0;
}

// ---------------------------------------------------------------------------
// Persistent recurrence: 127 GRU steps, both directions.
// 256 blocks x 512 thr, 1 block/CU. Weights LDS-resident, XOR-swizzled.
// K-loop order: positions 0..2 = xcat chunks (prefetched before the barrier),
// positions 3..10 = h chunks (depth-3 register pipeline, MALL loads).
// Per-mblk group barrier: 16 counters, 16 arrivals each.
// LDS: Bw 96x704 (135168 B) + As 2x64x64 (16384 B) = 151552 B.
// ---------------------------------------------------------------------------
__global__ __launch_bounds__(512)
void recurrence_kernel(const ushort_t* __restrict__ WhhB, const ushort_t* __restrict__ WihB,
                       const float* __restrict__ bih, const float* __restrict__ bhh,
                       const ushort_t* __restrict__ xcat_f, const ushort_t* __restrict__ xcat_b,
                       ushort_t* __restrict__ hfS, ushort_t* __restrict__ hbS,
                       unsigned* __restrict__ bar)
{
    extern __shared__ char smem_c[];
    ushort_t* Bw = (ushort_t*)smem_c;          // 96 x 704, col-chunk swizzled
    ushort_t* As = Bw + 96 * 704;              // 2 x 64 x 64, swizzled

    const int tid  = threadIdx.x;
    const int blk  = blockIdx.x;
    const int ublk = blk & 15;
    const int mblk = blk >> 4;
    const int u0   = ublk * 32;
    const bool fwd = (mblk < 8);
    const int rbase = (fwd ? mblk : mblk - 8) * 64;
    const ushort_t* xbase = fwd ? xcat_f : xcat_b;
    ushort_t* hS = fwd ? hfS : hbS;
    unsigned* gctr = bar + (unsigned)mblk * 64;   // per-group counter, 256B apart

    // weight preload (cached loads): row g*32+u -> [Whh(512) | Wih(192)]
    for (int i = tid; i < 96 * 88; i += 512) {
        int row = i / 88, q = i - row * 88;
        int g = row >> 5, u = u0 + (row & 31);
        const ushort_t* src = (q < 64)
            ? WhhB + ((size_t)(g * 512 + u)) * 512 + q * 8
            : WihB + ((size_t)(g * 512 + u)) * 192 + (q - 64) * 8;
        int qs = q ^ (row & 7);
        *(u32x4*)&Bw[row * 704 + qs * 8] = *(const u32x4*)src;
    }

    const int lane = tid & 63, wv = tid >> 6;
    const int mt = wv >> 1, tc = wv & 1;
    const int l15 = lane & 15, lhi = lane >> 4;
    const int arow = tid >> 3, aj = tid & 7;
    const int awoff = arow * 64 + ((aj ^ (arow & 7)) * 8);
    const int aSw = l15 & 7;

    const int u = u0 + tc * 16 + l15;
    const float bR  = bih[u] + bhh[u];
    const float bZ  = bih[512 + u] + bhh[512 + u];
    const float bNX = bih[1024 + u];
    const float bNH = bhh[1024 + u];

    f32x4 hreg = {0.f, 0.f, 0.f, 0.f};
    f32x4 zero = {0.f, 0.f, 0.f, 0.f};
    u32x4 r[3];

    // prologue: x chunks for step 0
    {
        const ushort_t* xr0 = xbase + (size_t)(rbase + arow) * 192 + aj * 8;
        r[0] = load_b128_mall(xr0);
        r[1] = load_b128_mall(xr0 + 64);
        r[2] = load_b128_mall(xr0 + 128);
        asm volatile("s_waitcnt vmcnt(0)" ::: "memory");
    }
    __syncthreads();   // weights staged

    for (int t = 0; t < 127; ++t) {
        const ushort_t* hrow = hS + (size_t)t * 262144 + (size_t)(rbase + arow) * 512 + aj * 8;
        ushort_t* hdst = hS + (size_t)(t + 1) * 262144;

        f32x4 accR = zero, accZ = zero, accNH = zero, accNX = zero;

        // stage x0 (position 0)
        *(u32x4*)&As[awoff] = r[0];
        __syncthreads();

        #pragma unroll
        for (int c = 0; c < 11; ++c) {
            // issue h prefetch for position c+3 (h chunk c)
            if (c <= 7) r[c % 3] = load_b128_mall(hrow + c * 64);

            // MFMA on position c from As[c&1]
            const ushort_t* Ab = As + (c & 1) * 4096;
            #pragma unroll
            for (int ks = 0; ks < 64; ks += 32) {
                int j  = (ks >> 3) + lhi;
                int jB = (c < 3) ? (64 + c * 8 + j) : ((c - 3) * 8 + j);
                bf16x8 a  = *(const bf16x8*)&Ab[(mt * 16 + l15) * 64 + ((j ^ aSw) * 8)];
                bf16x8 b0 = *(const bf16x8*)&Bw[( 0 + tc * 16 + l15) * 704 + ((jB ^ aSw) * 8)];
                bf16x8 b1 = *(const bf16x8*)&Bw[(32 + tc * 16 + l15) * 704 + ((jB ^ aSw) * 8)];
                bf16x8 b2 = *(const bf16x8*)&Bw[(64 + tc * 16 + l15) * 704 + ((jB ^ aSw) * 8)];
                accR = __builtin_amdgcn_mfma_f32_16x16x32_bf16(a, b0, accR, 0, 0, 0);
                accZ = __builtin_amdgcn_mfma_f32_16x16x32_bf16(a, b1, accZ, 0, 0, 0);
                if (c < 3) accNX = __builtin_amdgcn_mfma_f32_16x16x32_bf16(a, b2, accNX, 0, 0, 0);
                else       accNH = __builtin_amdgcn_mfma_f32_16x16x32_bf16(a, b2, accNH, 0, 0, 0);
            }

            // stage position c+1 into the other LDS buffer
            if (c < 10) {
                if (c <= 7)      { asm volatile("s_waitcnt vmcnt(2)" ::: "memory"); }
                else if (c == 8) { asm volatile("s_waitcnt vmcnt(1)" ::: "memory"); }
                else             { asm volatile("s_waitcnt vmcnt(0)" ::: "memory"); }
                *(u32x4*)&As[((c + 1) & 1) * 4096 + awoff] = r[(c + 1) % 3];
                __syncthreads();
            }
        }

        // GRU cell epilogue; fp32 state in registers; h out via MALL stores
        #pragma unroll
        for (int reg = 0; reg < 4; ++reg) {
            int m = rbase + mt * 16 + lhi * 4 + reg;
            float rr = fast_sigmoid(accR[reg] + bR);
            float zz = fast_sigmoid(accZ[reg] + bZ);
            float nn = fast_tanh(accNX[reg] + bNX + rr * (accNH[reg] + bNH));
            float hnew = (1.f - zz) * nn + zz * hreg[reg];
            hreg[reg] = hnew;
            store_b16_mall(hdst + (size_t)m * 512 + u, (unsigned)f2bf(hnew));
        }

        if (t < 126) {
            // prefetch next step's x chunks (no h dependency) across the barrier
            const ushort_t* xrn = xbase + (size_t)(t + 1) * 98304
                                + (size_t)(rbase + arow) * 192 + aj * 8;
            r[0] = load_b128_mall(xrn);
            r[1] = load_b128_mall(xrn + 64);
            r[2] = load_b128_mall(xrn + 128);

            asm volatile("s_waitcnt vmcnt(0)" ::: "memory");  // stores + x loads done
            __syncthreads();
            if (tid == 0) {
                atomicAdd(gctr, 1u);
                unsigned target = (unsigned)(t + 1) * 16u;
                while (__hip_atomic_load(gctr, __ATOMIC_RELAXED,
                                         __HIP_MEMORY_SCOPE_AGENT) < target)
                    __builtin_amdgcn_s_sleep(1);
            }
            __syncthreads();
        }
    }
}

// ---------------------------------------------------------------------------
// Fallback step kernel (used only if cooperative launch unavailable)
// ---------------------------------------------------------------------------
__global__ __launch_bounds__(512)
void step_kernel(const ushort_t* __restrict__ hsrcF, const ushort_t* __restrict__ hsrcB,
                 ushort_t* __restrict__ hdstF, ushort_t* __restrict__ hdstB,
                 const ushort_t* __restrict__ xF, const ushort_t* __restrict__ xB,
                 const ushort_t* __restrict__ WhhB, const ushort_t* __restrict__ WihB,
                 const float* __restrict__ bih, const float* __restrict__ bhh,
                 float* __restrict__ hstate)
{
    __shared__ __align__(16) ushort_t As[64 * 64];
    __shared__ __align__(16) ushort_t Bs[96 * 64];

    const int tid  = threadIdx.x;
    const int ublk = blockIdx.x;
    const int mblk = blockIdx.y;
    const int u0   = ublk * 32;
    const bool fwd = (mblk < 8);
    const ushort_t* hsrc = fwd ? hsrcF : hsrcB;
    const ushort_t* xsrc = fwd ? xF : xB;
    ushort_t* hdst = fwd ? hdstF : hdstB;
    const int rbase = (fwd ? mblk : mblk - 8) * 64;

    const int lane = tid & 63, wv = tid >> 6;
    const int mt = wv >> 1, tc = wv & 1;
    const int l15 = lane & 15, lhi = lane >> 4;

    f32x4 zero = {0.f, 0.f, 0.f, 0.f};
    f32x4 accR = zero, accZ = zero, accNH = zero, accNX = zero;
    const int arow = tid >> 3, ac8 = (tid & 7) * 8;

    for (int chunk = 0; chunk < 11; ++chunk) {
        const bool ph1 = (chunk < 8);
        {
            const ushort_t* src = ph1
                ? hsrc + ((size_t)(rbase + arow)) * 512 + chunk * 64 + ac8
                : xsrc + ((size_t)(rbase + arow)) * 192 + (chunk - 8) * 64 + ac8;
            *(uint4*)&As[arow * 64 + ac8] = *(const uint4*)src;
        }
        {
            int rowB = tid >> 3; int c8 = (tid & 7) * 8;
            int g = rowB >> 5; int u = u0 + (rowB & 31);
            const ushort_t* src = ph1
                ? WhhB + ((size_t)(g * 512 + u)) * 512 + chunk * 64 + c8
                : WihB + ((size_t)(g * 512 + u)) * 192 + (chunk - 8) * 64 + c8;
            *(uint4*)&Bs[rowB * 64 + c8] = *(const uint4*)src;
            if (tid < 256) {
                int u2 = tid + 512;
                rowB = u2 >> 3; c8 = (u2 & 7) * 8;
                g = rowB >> 5; u = u0 + (rowB & 31);
                src = ph1
                    ? WhhB + ((size_t)(g * 512 + u)) * 512 + chunk * 64 + c8
                    : WihB + ((size_t)(g * 512 + u)) * 192 + (chunk - 8) * 64 + c8;
                *(uint4*)&Bs[rowB * 64 + c8] = *(const uint4*)src;
            }
        }
        __syncthreads();
        #pragma unroll
        for (int ks = 0; ks < 64; ks += 32) {
            bf16x8 a  = *(const bf16x8*)&As[(mt * 16 + l15) * 64 + ks + lhi * 8];
            bf16x8 b0 = *(const bf16x8*)&Bs[( 0 + tc * 16 + l15) * 64 + ks + lhi * 8];
            bf16x8 b1 = *(const bf16x8*)&Bs[(32 + tc * 16 + l15) * 64 + ks + lhi * 8];
            bf16x8 b2 = *(const bf16x8*)&Bs[(64 + tc * 16 + l15) * 64 + ks + lhi * 8];
            accR = __builtin_amdgcn_mfma_f32_16x16x32_bf16(a, b0, accR, 0, 0, 0);
            accZ = __builtin_amdgcn_mfma_f32_16x16x32_bf16(a, b1, accZ, 0, 0, 0);
            if (ph1) accNH = __builtin_amdgcn_mfma_f32_16x16x32_bf16(a, b2, accNH, 0, 0, 0);
            else     accNX = __builtin_amdgcn_mfma_f32_16x16x32_bf16(a, b2, accNX, 0, 0, 0);
        }
        __syncthreads();
    }

    const int u = u0 + tc * 16 + l15;
    const float bR  = bih[u] + bhh[u];
    const float bZ  = bih[512 + u] + bhh[512 + u];
    const float bNX = bih[1024 + u];
    const float bNH = bhh[1024 + u];
    #pragma unroll
    for (int reg = 0; reg < 4; ++reg) {
        int m = mblk * 64 + mt * 16 + lhi * 4 + reg;
        float r = 1.f / (1.f + __expf(-(accR[reg] + bR)));
        float z = 1.f / (1.f + __expf(-(accZ[reg] + bZ)));
        float n = tanhf(accNX[reg] + bNX + r * (accNH[reg] + bNH));
        size_t idx = (size_t)m * 512 + u;
        float hold = hstate[idx];
        float hnew = (1.f - z) * n + z * hold;
        hstate[idx] = hnew;
        size_t bloc = (size_t)(fwd ? m : m - 512) * 512 + u;
        hdst[bloc] = f2bf(hnew);
    }
}

// ---------------------------------------------------------------------------
// x_v = [hf, hb_rev] @ Wh^T + bh, written as bf16 into pcat cols 59..117
// ---------------------------------------------------------------------------
__global__ __launch_bounds__(256)
void xv_kernel(const ushort_t* __restrict__ hf, const ushort_t* __restrict__ hb,
               const ushort_t* __restrict__ WhpB, const float* __restrict__ bh,
               ushort_t* __restrict__ pcat)
{
    __shared__ __align__(16) ushort_t As[128 * 64];
    __shared__ __align__(16) ushort_t Bs[64 * 64];
    const int b = blockIdx.x;
    const int tid = threadIdx.x;
    const int lane = tid & 63, wv = tid >> 6;
    const int l15 = lane & 15, lhi = lane >> 4;

    f32x4 zero = {0.f, 0.f, 0.f, 0.f};
    f32x4 acc[2][4];
    #pragma unroll
    for (int i = 0; i < 2; ++i)
        #pragma unroll
        for (int j = 0; j < 4; ++j) acc[i][j] = zero;

    for (int chunk = 0; chunk < 16; ++chunk) {
        const bool fw = (chunk < 8);
        #pragma unroll
        for (int s = 0; s < 4; ++s) {
            int unit = tid + s * 256;
            int row = unit >> 3;
            int c8 = (unit & 7) * 8;
            const ushort_t* src = fw
                ? hf + ((size_t)row * 512 + b) * 512 + chunk * 64 + c8
                : hb + ((size_t)(127 - row) * 512 + b) * 512 + (chunk - 8) * 64 + c8;
            *(uint4*)&As[row * 64 + c8] = *(const uint4*)src;
        }
        #pragma unroll
        for (int s = 0; s < 2; ++s) {
            int unit = tid + s * 256;
            int row = unit >> 3;
            int c8 = (unit & 7) * 8;
            *(uint4*)&Bs[row * 64 + c8] =
                *(const uint4*)(WhpB + (size_t)row * 1024 + chunk * 64 + c8);
        }
        __syncthreads();
        #pragma unroll
        for (int ks = 0; ks < 64; ks += 32) {
            bf16x8 bfr[4];
            #pragma unroll
            for (int nt = 0; nt < 4; ++nt)
                bfr[nt] = *(const bf16x8*)&Bs[(nt * 16 + l15) * 64 + ks + lhi * 8];
            #pragma unroll
            for (int mt2 = 0; mt2 < 2; ++mt2) {
                bf16x8 a = *(const bf16x8*)&As[(wv * 32 + mt2 * 16 + l15) * 64 + ks + lhi * 8];
                #pragma unroll
                for (int nt = 0; nt < 4; ++nt)
                    acc[mt2][nt] = __builtin_amdgcn_mfma_f32_16x16x32_bf16(a, bfr[nt], acc[mt2][nt], 0, 0, 0);
            }
        }
        __syncthreads();
    }
    #pragma unroll
    for (int mt2 = 0; mt2 < 2; ++mt2) {
        #pragma unroll
        for (int nt = 0; nt < 4; ++nt) {
            int col = nt * 16 + l15;
            if (col < 59) {
                float bhc = bh[col];
                #pragma unroll
                for (int reg = 0; reg < 4; ++reg) {
                    int t = wv * 32 + mt2 * 16 + lhi * 4 + reg;
                    pcat[((size_t)b * 128 + t) * 192 + 59 + col] = f2bf(acc[mt2][nt][reg] + bhc);
                }
            }
        }
    }
}

// ---------------------------------------------------------------------------
// Fused post: two chained MFMA GEMMs + x_imp + loss partials
// ---------------------------------------------------------------------------
__global__ __launch_bounds__(256)
void post_kernel(const ushort_t* __restrict__ pcat,
                 const ushort_t* __restrict__ Wpost1, const ushort_t* __restrict__ Wpost2,
                 const float* __restrict__ bcP, const float* __restrict__ biP,
                 const float* __restrict__ values, const float* __restrict__ masks,
                 float* __restrict__ out, float* __restrict__ pnum, float* __restrict__ pden)
{
    __shared__ __align__(16) ushort_t A1[64 * 200];
    __shared__ __align__(16) ushort_t B1[64 * 200];
    __shared__ __align__(16) ushort_t B2[64 * 72];

    const int tid = threadIdx.x;
    const int blk = blockIdx.x;
    const int lane = tid & 63, wv = tid >> 6;
    const int l15 = lane & 15, lhi = lane >> 4;

    #pragma unroll
    for (int s = 0; s < 6; ++s) {
        int unit = tid + s * 256;
        int row = unit / 24, c8 = (unit % 24) * 8;
        *(uint4*)&A1[row * 200 + c8] =
            *(const uint4*)(pcat + ((size_t)blk * 64 + row) * 192 + c8);
        *(uint4*)&B1[row * 200 + c8] =
            *(const uint4*)(Wpost1 + (size_t)row * 192 + c8);
    }
    #pragma unroll
    for (int s = 0; s < 2; ++s) {
        int unit = tid + s * 256;
        int row = unit >> 3, c8 = (unit & 7) * 8;
        *(uint4*)&B2[row * 72 + c8] = *(const uint4*)(Wpost2 + (size_t)row * 64 + c8);
    }
    __syncthreads();

    f32x4 zero = {0.f, 0.f, 0.f, 0.f};
    f32x4 acc1[4];
    #pragma unroll
    for (int nt = 0; nt < 4; ++nt) acc1[nt] = zero;

    #pragma unroll
    for (int ks = 0; ks < 192; ks += 32) {
        bf16x8 a = *(const bf16x8*)&A1[(wv * 16 + l15) * 200 + ks + lhi * 8];
        #pragma unroll
        for (int nt = 0; nt < 4; ++nt) {
            bf16x8 bb = *(const bf16x8*)&B1[(nt * 16 + l15) * 200 + ks + lhi * 8];
            acc1[nt] = __builtin_amdgcn_mfma_f32_16x16x32_bf16(a, bb, acc1[nt], 0, 0, 0);
        }
    }
    __syncthreads();

    #pragma unroll
    for (int nt = 0; nt < 4; ++nt) {
        int col = nt * 16 + l15;
        float bcv = bcP[col];
        #pragma unroll
        for (int reg = 0; reg < 4; ++reg) {
            int row = wv * 16 + lhi * 4 + reg;
            A1[row * 72 + col] = f2bf(acc1[nt][reg] + bcv);
        }
    }
    __syncthreads();

    f32x4 acc2[4];
    #pragma unroll
    for (int nt = 0; nt < 4; ++nt) acc2[nt] = zero;
    #pragma unroll
    for (int ks = 0; ks < 64; ks += 32) {
        bf16x8 a = *(const bf16x8*)&A1[(wv * 16 + l15) * 72 + ks + lhi * 8];
        #pragma unroll
        for (int nt = 0; nt < 4; ++nt) {
            bf16x8 bb = *(const bf16x8*)&B2[(nt * 16 + l15) * 72 + ks + lhi * 8];
            acc2[nt] = __builtin_amdgcn_mfma_f32_16x16x32_bf16(a, bb, acc2[nt], 0, 0, 0);
        }
    }

    float biR[4];
    #pragma unroll
    for (int nt = 0; nt < 4; ++nt) biR[nt] = biP[nt * 16 + l15];

    #pragma unroll
    for (int reg = 0; reg < 4; ++reg) {
        size_t rowg = (size_t)blk * 64 + wv * 16 + lhi * 4 + reg;
        float esum = 0.f, dsum = 0.f;
        #pragma unroll
        for (int nt = 0; nt < 4; ++nt) {
            int col = nt * 16 + l15;
            if (col < 59) {
                float imp = acc2[nt][reg] + biR[nt];
                float v = values[rowg * 59 + col];
                float m = masks [rowg * 59 + col];
                out[rowg * 59 + col] = m * v + (1.f - m) * imp;
                esum += fabsf(v - imp) * m;
                dsum += m;
            }
        }
        #pragma unroll
        for (int o = 1; o < 16; o <<= 1) {
            esum += __shfl_xor(esum, o);
            dsum += __shfl_xor(dsum, o);
        }
        if (l15 == 0) { pnum[rowg] = esum; pden[rowg] = dsum; }
    }
}

// ---------------------------------------------------------------------------
// loss reduction: sum_t ( sum_b num / (sum_b den + 1e-5) )
// ---------------------------------------------------------------------------
__global__ __launch_bounds__(512)
void loss_kernel(const float* __restrict__ pnum, const float* __restrict__ pden,
                 float* __restrict__ out)
{
    __shared__ float sn[512], sd[512];
    int tid = threadIdx.x;
    int t = tid & 127, q = tid >> 7;
    float a = 0.f, b = 0.f;
    for (int i = 0; i < 128; ++i) {
        int bb = q * 128 + i;
        a += pnum[(size_t)bb * 128 + t];
        b += pden[(size_t)bb * 128 + t];
    }
    sn[tid] = a; sd[tid] = b;
    __syncthreads();
    if (q == 0) {
        float A = sn[t] + sn[128 + t] + sn[256 + t] + sn[384 + t];
        float B = sd[t] + sd[128 + t] + sd[256 + t] + sd[384 + t];
        sn[t] = A / (B + 1e-5f);
    }
    __syncthreads();
    if (tid == 0) {
        float s = 0.f;
        for (int i = 0; i < 128; ++i) s += sn[i];
        out[3866624] = s;   // B*T*V
    }
}

// ---------------------------------------------------------------------------
extern "C" void kernel_launch(void* const* d_in, const int* in_sizes, int n_in,
                              void* d_out, int out_size, void* d_ws, size_t ws_size,
                              hipStream_t stream)
{
    const float* values   = (const float*)d_in[0];
    const float* masks    = (const float*)d_in[1];
    const float* deltas_f = (const float*)d_in[2];
    const float* deltas_b = (const float*)d_in[3];
    const float* Wih = (const float*)d_in[4];
    const float* Whh = (const float*)d_in[5];
    const float* bih = (const float*)d_in[6];
    const float* bhh = (const float*)d_in[7];
    const float* Wh  = (const float*)d_in[8];
    const float* bh  = (const float*)d_in[9];
    const float* Wf  = (const float*)d_in[10];
    const float* bf_ = (const float*)d_in[11];
    const float* Wc  = (const float*)d_in[12];
    const float* bc  = (const float*)d_in[13];
    const float* Wi  = (const float*)d_in[14];
    const float* bi  = (const float*)d_in[15];
    float* out = (float*)d_out;

    uint8_t* ws = (uint8_t*)d_ws;
    size_t off = 0;
    auto alloc = [&](size_t bytes) -> void* {
        void* p = ws + off;
        off = (off + bytes + 255) & ~((size_t)255);
        return p;
    };
    ushort_t* xcat_f = (ushort_t*)alloc(128ULL * 512 * 192 * 2);
    ushort_t* xcat_b = (ushort_t*)alloc(128ULL * 512 * 192 * 2);
    ushort_t* WhhB   = (ushort_t*)alloc(1536ULL * 512 * 2);
    ushort_t* WihB   = (ushort_t*)alloc(1536ULL * 192 * 2);
    ushort_t* WhpB   = (ushort_t*)alloc(64ULL * 1024 * 2);
    ushort_t* hfS    = (ushort_t*)alloc(128ULL * 512 * 512 * 2);
    ushort_t* hbS    = (ushort_t*)alloc(128ULL * 512 * 512 * 2);
    float*    hstate = (float*)alloc(1024ULL * 512 * 4);
    ushort_t* pcat   = (ushort_t*)alloc(65536ULL * 192 * 2);
    ushort_t* Wpost1 = (ushort_t*)alloc(64ULL * 192 * 2);
    ushort_t* Wpost2 = (ushort_t*)alloc(64ULL * 64 * 2);
    float*    bcP    = (float*)alloc(64 * 4);
    float*    biP    = (float*)alloc(64 * 4);
    float*    pnum   = (float*)alloc(65536ULL * 4);
    float*    pden   = (float*)alloc(65536ULL * 4);
    unsigned* bar    = (unsigned*)alloc(16 * 64 * 4);

    prep_small<<<1024, 256, 0, stream>>>(Wih, Whh, Wh, Wf, bf_, Wc, bc, Wi, bi,
                                         WhhB, WihB, WhpB, hfS, hbS, hstate,
                                         Wpost1, Wpost2, bcP, biP, bar);
    prep_panels<<<65536, 192, 0, stream>>>(values, masks, deltas_f, deltas_b,
                                           xcat_f, xcat_b, pcat);

    // Persistent recurrence (per-group barriers); fallback: 127 step launches
    const unsigned smemBytes = (96u * 704u + 2u * 64u * 64u) * 2u;  // 151552 B
    hipError_t aerr = hipFuncSetAttribute((const void*)recurrence_kernel,
                                          hipFuncAttributeMaxDynamicSharedMemorySize,
                                          (int)smemBytes);
    hipError_t lerr = hipErrorUnknown;
    if (aerr == hipSuccess) {
        const ushort_t* a0 = WhhB; const ushort_t* a1 = WihB;
        const float* a2 = bih; const float* a3 = bhh;
        const ushort_t* a4 = xcat_f; const ushort_t* a5 = xcat_b;
        ushort_t* a6 = hfS; ushort_t* a7 = hbS;
        unsigned* a8 = bar;
        void* args[] = { &a0, &a1, &a2, &a3, &a4, &a5, &a6, &a7, &a8 };
        lerr = hipLaunchCooperativeKernel((const void*)recurrence_kernel,
                                          dim3(256), dim3(512), args, smemBytes, stream);
    }
    if (lerr != hipSuccess) {
        for (int t = 0; t < 127; ++t) {
            step_kernel<<<dim3(16, 16), 512, 0, stream>>>(
                hfS + (size_t)t * 512 * 512, hbS + (size_t)t * 512 * 512,
                hfS + (size_t)(t + 1) * 512 * 512, hbS + (size_t)(t + 1) * 512 * 512,
                xcat_f + (size_t)t * 512 * 192, xcat_b + (size_t)t * 512 * 192,
                WhhB, WihB, bih, bhh, hstate);
        }
    }

    xv_kernel<<<512, 256, 0, stream>>>(hfS, hbS, WhpB, bh, pcat);
    post_kernel<<<1024, 256, 0, stream>>>(pcat, Wpost1, Wpost2, bcP, biP,
                                          values, masks, out, pnum, pden);
    loss_kernel<<<1, 512, 0, stream>>>(pnum, pden, out);
}